// Round 1
// baseline (48.793 us; speedup 1.0000x reference)
//
#include <hip/hip_runtime.h>
#include <math.h>

#define BS 8
#define N_PTS 8192
#define N_SAMPLES 2048
#define THREADS 256
#define SPT 8                    // samples per thread: 256*8 = 2048 = full batch per block
#define PSPLIT 64
#define CHUNK (N_PTS / PSPLIT)   // 128 points per block

// Kernel 1: per (batch, point-chunk) block, update running min dist^2 for all
// 2048 samples of the batch via atomicMin on float bits (non-negative -> uint
// compare preserves order; min is order-independent -> deterministic).
__global__ __launch_bounds__(THREADS)
void chamfer_min_kernel(const float* __restrict__ gts,
                        const float* __restrict__ preds,
                        const float* __restrict__ grid,
                        unsigned int* __restrict__ wsmin) // [2][BS][N_SAMPLES]
{
    const int bid = blockIdx.x;
    const int b   = bid / PSPLIT;
    const int pc  = bid % PSPLIT;
    const int t   = threadIdx.x;

    __shared__ float ldsP[CHUNK][4];   // padded to 4 floats -> ds_read_b128-friendly
    __shared__ float ldsG[CHUNK][4];

    // Cooperative staging of this block's point chunk (128 pred + 128 gts = 256 loads)
    {
        const float* pbase = preds + ((size_t)b * N_PTS + (size_t)pc * CHUNK) * 3;
        const float* gbase = gts   + ((size_t)b * N_PTS + (size_t)pc * CHUNK) * 3;
        if (t < CHUNK) {
            ldsP[t][0] = pbase[t * 3 + 0];
            ldsP[t][1] = pbase[t * 3 + 1];
            ldsP[t][2] = pbase[t * 3 + 2];
            ldsP[t][3] = 0.0f;
        } else {
            const int j = t - CHUNK;
            ldsG[j][0] = gbase[j * 3 + 0];
            ldsG[j][1] = gbase[j * 3 + 1];
            ldsG[j][2] = gbase[j * 3 + 2];
            ldsG[j][3] = 0.0f;
        }
    }

    // Load this thread's 8 sample coordinates (coalesced across lanes: s = k*256 + t)
    float sx[SPT], sy[SPT], sz[SPT], mP[SPT], mG[SPT];
    {
        const float* grow = grid + (size_t)b * N_SAMPLES * 3;
#pragma unroll
        for (int k = 0; k < SPT; ++k) {
            const int s = k * THREADS + t;
            sx[k] = grow[s * 3 + 0];
            sy[k] = grow[s * 3 + 1];
            sz[k] = grow[s * 3 + 2];
            mP[k] = 3.0e38f;
            mG[k] = 3.0e38f;
        }
    }

    __syncthreads();

    // Main loop: 128 points x (2 broadcast LDS b128 reads + 112 VALU ops)
#pragma unroll 2
    for (int j = 0; j < CHUNK; ++j) {
        const float px = ldsP[j][0], py = ldsP[j][1], pz = ldsP[j][2];
#pragma unroll
        for (int k = 0; k < SPT; ++k) {
            const float dx = sx[k] - px;
            const float dy = sy[k] - py;
            const float dz = sz[k] - pz;
            const float d2 = fmaf(dx, dx, fmaf(dy, dy, dz * dz));
            mP[k] = fminf(mP[k], d2);
        }
        const float gx = ldsG[j][0], gy = ldsG[j][1], gz = ldsG[j][2];
#pragma unroll
        for (int k = 0; k < SPT; ++k) {
            const float dx = sx[k] - gx;
            const float dy = sy[k] - gy;
            const float dz = sz[k] - gz;
            const float d2 = fmaf(dx, dx, fmaf(dy, dy, dz * dz));
            mG[k] = fminf(mG[k], d2);
        }
    }

    unsigned int* wp = wsmin + (size_t)b * N_SAMPLES;
    unsigned int* wg = wsmin + (size_t)(BS + b) * N_SAMPLES;
#pragma unroll
    for (int k = 0; k < SPT; ++k) {
        const int s = k * THREADS + t;
        atomicMin(&wp[s], __float_as_uint(mP[k]));
        atomicMin(&wg[s], __float_as_uint(mG[k]));
    }
}

// Kernel 2: per batch, |sqrt(minP2) - sqrt(minG2)| mean over samples.
__global__ __launch_bounds__(THREADS)
void chamfer_finish_kernel(const unsigned int* __restrict__ wsmin,
                           float* __restrict__ out)
{
    const int b = blockIdx.x;
    const int t = threadIdx.x;
    const unsigned int* wp = wsmin + (size_t)b * N_SAMPLES;
    const unsigned int* wg = wsmin + (size_t)(BS + b) * N_SAMPLES;

    float sum = 0.0f;
#pragma unroll
    for (int s = t; s < N_SAMPLES; s += THREADS) {
        const float dp = sqrtf(__uint_as_float(wp[s]));
        const float dg = sqrtf(__uint_as_float(wg[s]));
        sum += fabsf(dp - dg);
    }

    // wave (64-lane) reduction, fixed tree -> deterministic
#pragma unroll
    for (int off = 32; off > 0; off >>= 1)
        sum += __shfl_down(sum, off, 64);

    __shared__ float wsum[THREADS / 64];
    const int wid = t >> 6;
    if ((t & 63) == 0) wsum[wid] = sum;
    __syncthreads();
    if (t == 0) {
        float tot = 0.0f;
#pragma unroll
        for (int w = 0; w < THREADS / 64; ++w) tot += wsum[w];
        out[b] = tot / (float)N_SAMPLES;
    }
}

extern "C" void kernel_launch(void* const* d_in, const int* in_sizes, int n_in,
                              void* d_out, int out_size, void* d_ws, size_t ws_size,
                              hipStream_t stream)
{
    const float* gts   = (const float*)d_in[0];
    const float* preds = (const float*)d_in[1];
    const float* grid  = (const float*)d_in[2];
    float* out = (float*)d_out;
    unsigned int* wsmin = (unsigned int*)d_ws;

    const size_t wsbytes = (size_t)2 * BS * N_SAMPLES * sizeof(unsigned int); // 128 KiB
    // 0x7F7F7F7F as float = 3.39e38 -> acts as +inf for min of real dist^2
    hipMemsetAsync(d_ws, 0x7F, wsbytes, stream);

    chamfer_min_kernel<<<dim3(BS * PSPLIT), dim3(THREADS), 0, stream>>>(gts, preds, grid, wsmin);
    chamfer_finish_kernel<<<dim3(BS), dim3(THREADS), 0, stream>>>(wsmin, out);
}

// Round 2
// 34.251 us; speedup vs baseline: 1.4246x; 1.4246x over previous
//
#include <hip/hip_runtime.h>
#include <math.h>

#define BS 8
#define N_PTS 8192
#define N_SAMPLES 2048
#define THREADS 256
#define SPT 8                    // samples per thread: 256*8 = 2048 = full batch per block
#define PSPLIT 64
#define CHUNK (N_PTS / PSPLIT)   // 128 points per block

// Kernel 1: per (batch, point-chunk) block. Candidate metric per pair is
//   f = |p|^2 - 2 s.p   (monotone in d^2 for fixed s; d^2 = f + |s|^2)
// -> 3 fma + min per pair instead of 3 sub + 2 fma + mul + min.
// |s|^2 is added (and clamped >=0) AFTER the per-thread min, so the uint-bit
// atomicMin sees only non-negative floats (order-preserving, deterministic).
__global__ __launch_bounds__(THREADS, 1)
void chamfer_min_kernel(const float* __restrict__ gts,
                        const float* __restrict__ preds,
                        const float* __restrict__ grid,
                        unsigned int* __restrict__ wsmin) // [2][BS][N_SAMPLES]
{
    const int bid = blockIdx.x;
    const int b   = bid / PSPLIT;
    const int pc  = bid % PSPLIT;
    const int t   = threadIdx.x;

    __shared__ float4 ldsP[CHUNK];   // {px, py, pz, |p|^2}
    __shared__ float4 ldsG[CHUNK];

    // Cooperative staging: threads 0..127 stage preds, 128..255 stage gts.
    {
        const int j = t & (CHUNK - 1);
        const float* src = (t < CHUNK)
            ? preds + ((size_t)b * N_PTS + (size_t)pc * CHUNK) * 3
            : gts   + ((size_t)b * N_PTS + (size_t)pc * CHUNK) * 3;
        const float x = src[j * 3 + 0];
        const float y = src[j * 3 + 1];
        const float z = src[j * 3 + 2];
        const float hp = fmaf(x, x, fmaf(y, y, z * z));
        const float4 v = make_float4(x, y, z, hp);
        if (t < CHUNK) ldsP[j] = v; else ldsG[j] = v;
    }

    // Per-thread samples: ns = -2*s (s recovered in epilogue via |s|^2 = 0.25*|ns|^2)
    float nsx[SPT], nsy[SPT], nsz[SPT], mP[SPT], mG[SPT];
    {
        const float* grow = grid + (size_t)b * N_SAMPLES * 3;
#pragma unroll
        for (int k = 0; k < SPT; ++k) {
            const int s = k * THREADS + t;
            nsx[k] = -2.0f * grow[s * 3 + 0];
            nsy[k] = -2.0f * grow[s * 3 + 1];
            nsz[k] = -2.0f * grow[s * 3 + 2];
            mP[k] = 3.0e38f;
            mG[k] = 3.0e38f;
        }
    }

    __syncthreads();

    // Main loop: 2 points per iter per side; 3 fma + shared min3 per pair.
#pragma unroll 2
    for (int j = 0; j < CHUNK; j += 2) {
        const float4 p0 = ldsP[j], p1 = ldsP[j + 1];
        const float4 g0 = ldsG[j], g1 = ldsG[j + 1];
#pragma unroll
        for (int k = 0; k < SPT; ++k) {
            const float t0 = fmaf(p0.x, nsx[k], fmaf(p0.y, nsy[k], fmaf(p0.z, nsz[k], p0.w)));
            const float t1 = fmaf(p1.x, nsx[k], fmaf(p1.y, nsy[k], fmaf(p1.z, nsz[k], p1.w)));
            mP[k] = fminf(fminf(t0, t1), mP[k]);   // -> v_min3_f32
            const float u0 = fmaf(g0.x, nsx[k], fmaf(g0.y, nsy[k], fmaf(g0.z, nsz[k], g0.w)));
            const float u1 = fmaf(g1.x, nsx[k], fmaf(g1.y, nsy[k], fmaf(g1.z, nsz[k], g1.w)));
            mG[k] = fminf(fminf(u0, u1), mG[k]);
        }
    }

    unsigned int* wp = wsmin + (size_t)b * N_SAMPLES;
    unsigned int* wg = wsmin + (size_t)(BS + b) * N_SAMPLES;
#pragma unroll
    for (int k = 0; k < SPT; ++k) {
        const int s = k * THREADS + t;
        const float s2 = 0.25f * fmaf(nsx[k], nsx[k], fmaf(nsy[k], nsy[k], nsz[k] * nsz[k]));
        atomicMin(&wp[s], __float_as_uint(fmaxf(mP[k] + s2, 0.0f)));
        atomicMin(&wg[s], __float_as_uint(fmaxf(mG[k] + s2, 0.0f)));
    }
}

// Kernel 2: per batch, |sqrt(minP2) - sqrt(minG2)| mean over samples.
__global__ __launch_bounds__(THREADS)
void chamfer_finish_kernel(const unsigned int* __restrict__ wsmin,
                           float* __restrict__ out)
{
    const int b = blockIdx.x;
    const int t = threadIdx.x;
    const unsigned int* wp = wsmin + (size_t)b * N_SAMPLES;
    const unsigned int* wg = wsmin + (size_t)(BS + b) * N_SAMPLES;

    float sum = 0.0f;
#pragma unroll
    for (int s = t; s < N_SAMPLES; s += THREADS) {
        const float dp = sqrtf(__uint_as_float(wp[s]));
        const float dg = sqrtf(__uint_as_float(wg[s]));
        sum += fabsf(dp - dg);
    }

    // wave (64-lane) reduction, fixed tree -> deterministic
#pragma unroll
    for (int off = 32; off > 0; off >>= 1)
        sum += __shfl_down(sum, off, 64);

    __shared__ float wsum[THREADS / 64];
    const int wid = t >> 6;
    if ((t & 63) == 0) wsum[wid] = sum;
    __syncthreads();
    if (t == 0) {
        float tot = 0.0f;
#pragma unroll
        for (int w = 0; w < THREADS / 64; ++w) tot += wsum[w];
        out[b] = tot / (float)N_SAMPLES;
    }
}

extern "C" void kernel_launch(void* const* d_in, const int* in_sizes, int n_in,
                              void* d_out, int out_size, void* d_ws, size_t ws_size,
                              hipStream_t stream)
{
    const float* gts   = (const float*)d_in[0];
    const float* preds = (const float*)d_in[1];
    const float* grid  = (const float*)d_in[2];
    float* out = (float*)d_out;
    unsigned int* wsmin = (unsigned int*)d_ws;

    const size_t wsbytes = (size_t)2 * BS * N_SAMPLES * sizeof(unsigned int); // 128 KiB
    // 0x7F7F7F7F as float = 3.39e38 -> acts as +inf for min of clamped metric
    hipMemsetAsync(d_ws, 0x7F, wsbytes, stream);

    chamfer_min_kernel<<<dim3(BS * PSPLIT), dim3(THREADS), 0, stream>>>(gts, preds, grid, wsmin);
    chamfer_finish_kernel<<<dim3(BS), dim3(THREADS), 0, stream>>>(wsmin, out);
}